// Round 1
// baseline (1527.278 us; speedup 1.0000x reference)
//
#include <hip/hip_runtime.h>

#define NPTS 100000
#define PTILES 6250     // NPTS/16
#define NSEG 160        // 1280/8
#define INF 1280
#define OUTF 256

using short8 = __attribute__((ext_vector_type(8))) short;
using f32x4  = __attribute__((ext_vector_type(4))) float;

__device__ __forceinline__ unsigned short f2bf(float x) {
  unsigned u = __float_as_uint(x);
  return (unsigned short)((u + 0x7FFFu + ((u >> 16) & 1u)) >> 16);  // RNE
}

__device__ __forceinline__ void gl_lds16(const void* g, void* l) {
  __builtin_amdgcn_global_load_lds(
      (const __attribute__((address_space(1))) unsigned int*)g,
      (__attribute__((address_space(3))) unsigned int*)l, 16, 0, 0);
}

// ---------------- kernel 0: retile linear_weights -> bf16 fragment order ---
// Wb[nt][kseg][col][j] = bf16(W[nt*16+col][kseg*8+j]); per-nt block = 160*16*8
__global__ void k_wconv(const float* __restrict__ W, unsigned short* __restrict__ Wb) {
  int g = blockIdx.x * 256 + threadIdx.x;          // 0..327679
  int j = g & 7;
  int col = (g >> 3) & 15;
  int kseg = (g >> 7) % NSEG;
  int nt = g / (NSEG * 128);
  Wb[g] = f2bf(W[(nt * 16 + col) * INF + kseg * 8 + j]);
}

// ---------------- kernel 1: gather + concat + pconv -> tiled bf16 A --------
// A layout: [ptile][kseg 0..159][row 0..15][8 bf16], kseg = c*2 + m/8, j = m%8
#define FP 176    // bytes per point row in feat LDS (80 bf16 + 8 pad)
#define FK 2816   // 16*FP (k stride)
#define WP 80     // bytes per point row in wn LDS (16 f32 + 4 pad)
#define WK 1280   // 16*WP (k stride)

__global__ __launch_bounds__(320) void k_pconv(
    const float* __restrict__ in_f, const int* __restrict__ nbr,
    const float* __restrict__ wn_g, const float* __restrict__ add_f,
    unsigned short* __restrict__ A, int pt0)
{
  __shared__ __align__(16) unsigned char s_feat[45056];  // [k][p][c] bf16, padded
  __shared__ __align__(16) unsigned char s_wn[20480];    // [k][p][m] f32, padded
  const int t = threadIdx.x;
  const int lpt = blockIdx.x;
  const long p0 = (long)(pt0 + lpt) * 16;  // first global point of this tile

  // stage weightnet (f32) -> LDS [k][p][m]
  for (int g = t; g < 4096; g += 320) {
    int p = g >> 8, k = (g >> 4) & 15, m = g & 15;
    float v = wn_g[(p0 + p) * 256 + k * 16 + m];
    *(float*)(s_wn + k * WK + p * WP + m * 4) = v;
  }
  // stage feat = concat(gather(in_f), add_f) -> LDS bf16 [k][p][c]
  const int wave = t >> 6, lane = t & 63;
  for (int r = wave; r < 256; r += 5) {      // r = p*16 + k
    int p = r >> 4, k = r & 15;
    if (lane < 40) {
      float2 v;
      if (lane < 32) {
        int idx = nbr[(p0 + p) * 16 + k];
        v = *(const float2*)(in_f + (long)idx * 64 + lane * 2);
      } else {
        v = *(const float2*)(add_f + ((p0 + p) * 16 + k) * 16 + (lane - 32) * 2);
      }
      unsigned pk = (unsigned)f2bf(v.x) | ((unsigned)f2bf(v.y) << 16);
      *(unsigned*)(s_feat + k * FK + p * FP + lane * 4) = pk;
    }
  }
  __syncthreads();

  // compute: thread = (point p, c-block of 8, m-block of 8)
  const int p = t & 15;
  const int sub = t >> 4;                 // 0..19
  const int cg = sub % 10, mg = sub / 10; // c0 = 8*cg, m0 = 8*mg
  const unsigned char* fb = s_feat + p * FP + cg * 16;
  const unsigned char* wb = s_wn + p * WP + mg * 32;

  float acc[8][8];
#pragma unroll
  for (int i = 0; i < 8; ++i)
#pragma unroll
    for (int j = 0; j < 8; ++j) acc[i][j] = 0.f;

#pragma unroll
  for (int k = 0; k < 16; ++k) {
    uint4 fv = *(const uint4*)(fb + k * FK);
    float4 w0 = *(const float4*)(wb + k * WK);
    float4 w1 = *(const float4*)(wb + k * WK + 16);
    float f[8], w[8];
    f[0] = __uint_as_float(fv.x << 16);
    f[1] = __uint_as_float(fv.x & 0xFFFF0000u);
    f[2] = __uint_as_float(fv.y << 16);
    f[3] = __uint_as_float(fv.y & 0xFFFF0000u);
    f[4] = __uint_as_float(fv.z << 16);
    f[5] = __uint_as_float(fv.z & 0xFFFF0000u);
    f[6] = __uint_as_float(fv.w << 16);
    f[7] = __uint_as_float(fv.w & 0xFFFF0000u);
    w[0] = w0.x; w[1] = w0.y; w[2] = w0.z; w[3] = w0.w;
    w[4] = w1.x; w[5] = w1.y; w[6] = w1.z; w[7] = w1.w;
#pragma unroll
    for (int ci = 0; ci < 8; ++ci)
#pragma unroll
      for (int mi = 0; mi < 8; ++mi)
        acc[ci][mi] = fmaf(f[ci], w[mi], acc[ci][mi]);
  }

  // write pconv tile (bf16, MFMA-A-fragment-friendly tiled layout)
#pragma unroll
  for (int ci = 0; ci < 8; ++ci) {
    int c = cg * 8 + ci;
    int kseg = c * 2 + mg;
    unsigned r0 = (unsigned)f2bf(acc[ci][0]) | ((unsigned)f2bf(acc[ci][1]) << 16);
    unsigned r1 = (unsigned)f2bf(acc[ci][2]) | ((unsigned)f2bf(acc[ci][3]) << 16);
    unsigned r2 = (unsigned)f2bf(acc[ci][4]) | ((unsigned)f2bf(acc[ci][5]) << 16);
    unsigned r3 = (unsigned)f2bf(acc[ci][6]) | ((unsigned)f2bf(acc[ci][7]) << 16);
    uint4 val = make_uint4(r0, r1, r2, r3);
    *(uint4*)(A + (((long)lpt * NSEG + kseg) * 16 + p) * 8) = val;
  }
}

// ---------------- kernel 2: out = A(bf16) @ Wb^T + bias via MFMA -----------
// block: 512 thr = 8 waves, M_TILE=128 (wave -> 1 ptile of 16 rows), N=256
__global__ __launch_bounds__(512) void k_gemm(
    const unsigned short* __restrict__ A, const unsigned short* __restrict__ Wb,
    const float* __restrict__ bias, float* __restrict__ out, int pt0)
{
  __shared__ __align__(16) unsigned short sB[2][16 * 512];  // 2 x 16KB
  const int t = threadIdx.x;
  const int wave = t >> 6, lane = t & 63;
  const int lpt = blockIdx.x * 8 + wave;
  const unsigned short* Ab = A + (long)lpt * 20480;  // 160*16*8 per ptile

  f32x4 acc[16];
#pragma unroll
  for (int i = 0; i < 16; ++i) acc[i] = f32x4{0.f, 0.f, 0.f, 0.f};

  auto stage = [&](int ks, int bufi) {
#pragma unroll
    for (int i = 0; i < 2; ++i) {
      int flat = i * 512 + t;
      const unsigned short* src = Wb + (flat >> 6) * 20480 + ks * 512 + (flat & 63) * 8;
      gl_lds16(src, &sB[bufi][(size_t)(i * 512 + wave * 64) * 8]);
    }
  };

  stage(0, 0);
  asm volatile("s_waitcnt vmcnt(0)" ::: "memory");
  __syncthreads();

  for (int ks = 0; ks < 40; ++ks) {
    int cur = ks & 1;
    if (ks + 1 < 40) stage(ks + 1, cur ^ 1);  // prefetch next W tile
    short8 a = *(const short8*)(Ab + ks * 512 + lane * 8);  // coalesced 1KB/wave
#pragma unroll
    for (int nt = 0; nt < 16; ++nt) {
      short8 b = *(const short8*)(&sB[cur][(size_t)(nt * 64 + lane) * 8]);
      acc[nt] = __builtin_amdgcn_mfma_f32_16x16x32_bf16(a, b, acc[nt], 0, 0, 0);
    }
    asm volatile("s_waitcnt vmcnt(0)" ::: "memory");
    __syncthreads();
  }

  // epilogue: C/D layout col=lane&15, row=(lane>>4)*4+r (m89-verified)
  const int col = lane & 15, rg = lane >> 4;
  const long row0 = (long)(pt0 + blockIdx.x * 8 + wave) * 16;
#pragma unroll
  for (int nt = 0; nt < 16; ++nt) {
    int n = nt * 16 + col;
    float bv = bias[n];
#pragma unroll
    for (int r = 0; r < 4; ++r) {
      long prow = row0 + rg * 4 + r;
      if (prow < NPTS) out[prow * 256 + n] = acc[nt][r] + bv;
    }
  }
}

extern "C" void kernel_launch(void* const* d_in, const int* in_sizes, int n_in,
                              void* d_out, int out_size, void* d_ws, size_t ws_size,
                              hipStream_t stream) {
  const float* in_f  = (const float*)d_in[0];
  const int*   nbr   = (const int*)d_in[1];
  const float* wn    = (const float*)d_in[5];
  const float* add_f = (const float*)d_in[6];
  const float* W     = (const float*)d_in[7];
  const float* bias  = (const float*)d_in[8];
  float* out = (float*)d_out;

  const size_t WB_BYTES = 16l * NSEG * 16 * 8 * 2;  // 655360
  const size_t PT_BYTES = 40960;                    // bytes per ptile in A
  long T = 0;
  if (ws_size > WB_BYTES + 64) T = (long)((ws_size - WB_BYTES - 64) / PT_BYTES);
  if (T > 6256) T = 6256;   // PTILES padded to multiple of 8
  T &= ~7l;
  if (T < 8) T = 8;

  unsigned short* Abuf = (unsigned short*)d_ws;
  unsigned short* Wb = (unsigned short*)((char*)d_ws + (size_t)T * PT_BYTES);

  k_wconv<<<dim3(1280), dim3(256), 0, stream>>>(W, Wb);

  int nchunks = (int)((PTILES + T - 1) / T);
  for (int c = 0; c < nchunks; ++c) {
    long p0 = (long)c * T;
    long np = PTILES - p0; if (np > T) np = T;
    k_pconv<<<dim3((unsigned)np), dim3(320), 0, stream>>>(in_f, nbr, wn, add_f, Abuf, (int)p0);
    k_gemm<<<dim3((unsigned)((np + 7) / 8)), dim3(512), 0, stream>>>(Abuf, Wb, bias, out, (int)p0);
  }
}

// Round 2
// 253.860 us; speedup vs baseline: 6.0162x; 6.0162x over previous
//
#include <hip/hip_runtime.h>

#define NPTS 100000
#define PB 64                         // points per block
#define NBLK ((NPTS + PB - 1) / PB)   // 1563
#define INF 1280
#define OUTF 256

using short8 = __attribute__((ext_vector_type(8))) short;
using f32x4  = __attribute__((ext_vector_type(4))) float;

__device__ __forceinline__ unsigned short f2bf(float x) {
  unsigned u = __float_as_uint(x);
  return (unsigned short)((u + 0x7FFFu + ((u >> 16) & 1u)) >> 16);  // RNE
}

// ---- prep: in_f f32 -> bf16 (12.8 MB, L3-resident for gathers) ----
__global__ void k_prep(const float* __restrict__ in_f, unsigned short* __restrict__ inbf) {
  int i = blockIdx.x * 256 + threadIdx.x;   // one float4 each; 1.6M total
  if (i < 1600000) {
    float4 v = ((const float4*)in_f)[i];
    ushort4 o;
    o.x = f2bf(v.x); o.y = f2bf(v.y); o.z = f2bf(v.z); o.w = f2bf(v.w);
    ((ushort4*)inbf)[i] = o;
  }
}

// ---- retile linear_weights -> bf16 B-fragment order ----
// Wb[nt][ct][ks 0..31][col 0..15][j 0..7]; k^ = ks*8+j; m=k^>>4; ci=k^&15;
// source col = (ct*16+ci)*16 + m  (reference flattening c*16+m)
__global__ void k_wconv(const float* __restrict__ W, unsigned short* __restrict__ Wb) {
  int g = blockIdx.x * 256 + threadIdx.x;   // 0..327679
  int j = g & 7;
  int col = (g >> 3) & 15;
  int ks = (g >> 7) & 31;
  int rest = g >> 12;
  int ct = rest % 5, nt = rest / 5;
  int kh = ks * 8 + j;
  int m = kh >> 4, ci = kh & 15;
  Wb[g] = f2bf(W[(nt * 16 + col) * INF + (ct * 16 + ci) * 16 + m]);
}

// ---- fused: gather+concat+pconv (MFMA) + linear (MFMA), phased over c ----
__global__ __launch_bounds__(512, 4) void k_fused(
    const unsigned short* __restrict__ inbf, const int* __restrict__ nbr,
    const float* __restrict__ wn_g, const float* __restrict__ add_f,
    const unsigned short* __restrict__ Wb, const float* __restrict__ bias,
    float* __restrict__ out)
{
  __shared__ __align__(16) unsigned char sA[PB * 528];  // A-slice [p][k^256 bf16], 528B stride (bank-safe)
  __shared__ __align__(16) unsigned char sW[PB * 512];  // wn bf16 [p][m16][k16]
  __shared__ int s_nbr[PB * 16];

  const int t = threadIdx.x;
  const int w = t >> 6, lane = t & 63;
  const int g16 = lane >> 4;   // k-group / row-group
  const int c16 = lane & 15;   // col-within-16
  const long p0 = (long)blockIdx.x * PB;

  // stage neighbor indices (clamped for tail)
  for (int i = t; i < PB * 16; i += 512) {
    long pp = p0 + (i >> 4); if (pp >= NPTS) pp = NPTS - 1;
    s_nbr[i] = nbr[pp * 16 + (i & 15)];
  }
  // stage weightnet f32 -> bf16, transposed to [p][m][k]
#pragma unroll
  for (int it = 0; it < 8; ++it) {
    int flat4 = it * 512 + t;                 // 4096 float4 total
    int p = flat4 >> 6, k = (flat4 >> 2) & 15, m4 = (flat4 & 3) * 4;
    long pp = p0 + p; if (pp >= NPTS) pp = NPTS - 1;
    float4 v = *(const float4*)(wn_g + pp * 256 + k * 16 + m4);
    unsigned short* wb = (unsigned short*)(sW + p * 512 + k * 2);
    wb[(m4 + 0) * 16] = f2bf(v.x);
    wb[(m4 + 1) * 16] = f2bf(v.y);
    wb[(m4 + 2) * 16] = f2bf(v.z);
    wb[(m4 + 3) * 16] = f2bf(v.w);
  }
  __syncthreads();

  f32x4 acc[2][4];
#pragma unroll
  for (int a = 0; a < 2; ++a)
#pragma unroll
    for (int b = 0; b < 4; ++b) acc[a][b] = (f32x4){0.f, 0.f, 0.f, 0.f};

  const int rt0 = (w & 1) * 2;       // first of 2 row-tiles (16 points each)
  const int nt0 = (w >> 1) * 4;      // first of 4 col-tiles

  for (int ct = 0; ct < 5; ++ct) {
    // ---- pconv: each wave owns points w*8 .. w*8+7 ----
#pragma unroll 2
    for (int i = 0; i < 8; ++i) {
      int p = w * 8 + i;
      long pp = p0 + p; if (pp >= NPTS) pp = NPTS - 1;
      short8 af = (short8){0, 0, 0, 0, 0, 0, 0, 0};
      short8 bf = (short8){0, 0, 0, 0, 0, 0, 0, 0};
      if (g16 < 2) {
        bf = *(const short8*)(sW + p * 512 + c16 * 32 + g16 * 16);
        int4 i0 = *(const int4*)&s_nbr[p * 16 + g16 * 8];
        int4 i1 = *(const int4*)&s_nbr[p * 16 + g16 * 8 + 4];
        unsigned short a8[8];
        if (ct < 4) {
          a8[0] = inbf[(long)i0.x * 64 + ct * 16 + c16];
          a8[1] = inbf[(long)i0.y * 64 + ct * 16 + c16];
          a8[2] = inbf[(long)i0.z * 64 + ct * 16 + c16];
          a8[3] = inbf[(long)i0.w * 64 + ct * 16 + c16];
          a8[4] = inbf[(long)i1.x * 64 + ct * 16 + c16];
          a8[5] = inbf[(long)i1.y * 64 + ct * 16 + c16];
          a8[6] = inbf[(long)i1.z * 64 + ct * 16 + c16];
          a8[7] = inbf[(long)i1.w * 64 + ct * 16 + c16];
        } else {
#pragma unroll
          for (int j = 0; j < 8; ++j)
            a8[j] = f2bf(add_f[(pp * 16 + g16 * 8 + j) * 16 + c16]);
        }
#pragma unroll
        for (int j = 0; j < 8; ++j) ((unsigned short*)&af)[j] = a8[j];
      }
      f32x4 d = __builtin_amdgcn_mfma_f32_16x16x32_bf16(af, bf, (f32x4){0.f, 0.f, 0.f, 0.f}, 0, 0, 0);
      // D: row(=ci)=g16*4+r, col(=m)=c16 ; k^ = m*16+ci -> bytes c16*32 + g16*8 + r*2
      unsigned lo = (unsigned)f2bf(d[0]) | ((unsigned)f2bf(d[1]) << 16);
      unsigned hi = (unsigned)f2bf(d[2]) | ((unsigned)f2bf(d[3]) << 16);
      *(uint2*)(sA + p * 528 + c16 * 32 + g16 * 8) = make_uint2(lo, hi);
    }
    __syncthreads();   // A-slice complete

    // ---- GEMM over this 256-wide k^ slice: 8 ksteps, no barriers ----
#pragma unroll
    for (int kl = 0; kl < 8; ++kl) {
      short8 a0 = *(const short8*)(sA + (rt0 * 16 + c16) * 528 + kl * 64 + g16 * 16);
      short8 a1 = *(const short8*)(sA + ((rt0 + 1) * 16 + c16) * 528 + kl * 64 + g16 * 16);
#pragma unroll
      for (int ntl = 0; ntl < 4; ++ntl) {
        int nt = nt0 + ntl;
        short8 b = *(const short8*)(Wb + (((long)(nt * 5 + ct) * 32 + kl * 4 + g16) * 16 + c16) * 8);
        acc[0][ntl] = __builtin_amdgcn_mfma_f32_16x16x32_bf16(a0, b, acc[0][ntl], 0, 0, 0);
        acc[1][ntl] = __builtin_amdgcn_mfma_f32_16x16x32_bf16(a1, b, acc[1][ntl], 0, 0, 0);
      }
    }
    __syncthreads();   // before next phase overwrites sA
  }

  // ---- epilogue: bias + store ----
#pragma unroll
  for (int ntl = 0; ntl < 4; ++ntl) {
    int n = nt0 * 16 + ntl * 16 + c16;
    float bv = bias[n];
#pragma unroll
    for (int rr = 0; rr < 2; ++rr) {
      long prow = p0 + (rt0 + rr) * 16 + g16 * 4;
#pragma unroll
      for (int r = 0; r < 4; ++r) {
        if (prow + r < NPTS) out[(prow + r) * 256 + n] = acc[rr][ntl][r] + bv;
      }
    }
  }
}

extern "C" void kernel_launch(void* const* d_in, const int* in_sizes, int n_in,
                              void* d_out, int out_size, void* d_ws, size_t ws_size,
                              hipStream_t stream) {
  const float* in_f  = (const float*)d_in[0];
  const int*   nbr   = (const int*)d_in[1];
  const float* wn    = (const float*)d_in[5];
  const float* add_f = (const float*)d_in[6];
  const float* W     = (const float*)d_in[7];
  const float* bias  = (const float*)d_in[8];
  float* out = (float*)d_out;

  unsigned short* inbf = (unsigned short*)d_ws;                       // 12.8 MB
  unsigned short* Wb   = (unsigned short*)((char*)d_ws + 13631488);   // 640 KB

  k_prep<<<dim3(6250), dim3(256), 0, stream>>>(in_f, inbf);
  k_wconv<<<dim3(1280), dim3(256), 0, stream>>>(W, Wb);
  k_fused<<<dim3(NBLK), dim3(512), 0, stream>>>(inbf, nbr, wn, add_f, Wb, bias, out);
}